// Round 4
// baseline (4952.703 us; speedup 1.0000x reference)
//
#include <hip/hip_runtime.h>
#include <cstddef>

#define T_STEPS 90
#define BT      2048
#define NXV     144
#define HV      128
#define NZV     128
#define M1V     300
#define M2V     200
#define NB      16     // batches per workgroup (16 = full MFMA N-dim)
#define NTH     512    // 8 waves

typedef __attribute__((ext_vector_type(8))) short short8v;   // 8 bf16
typedef __attribute__((ext_vector_type(4))) float f32x4;

// ---- 12 fragment streams: geometry ----
// g: 0 ENC_IH 1 ENC_HH 2 W1E 3 W2E 4 MU 5 LV 6 DEC_IHX 7 DEC_IHZ 8 DEC_HH 9 W1D 10 W2D 11 WO
constexpr int MTa[12]   = {24,24,19,13, 8, 8,24,24,24,19,13, 9};
constexpr int KTa[12]   = { 5, 5, 5,10, 7, 7, 5, 5, 5, 5,10, 7};
constexpr int MREAL[12] = {384,384,300,200,128,128,384,384,384,300,200,144};
constexpr int KREAL[12] = {144,128,128,300,200,200,144,128,128,128,300,200};
constexpr int RSW[12]   = {144,128,128,300,200,200,272,272,128,128,300,200};
constexpr int COW[12]   = {  0,  0,  0,  0,  0,  0,  0,144,  0,  0,  0,  0};
constexpr int P13[13]   = {0,120,240,335,465,521,577,697,817,937,1032,1162,1225};
constexpr int NFRAG = 1225;   // total frags (hi); lo mirrored at +NFRAG. ws = 2*1225 KB

__device__ __forceinline__ unsigned short bfhi(float f) {
    unsigned int u = __float_as_uint(f);
    u += 0x7FFF + ((u >> 16) & 1);          // RNE to bf16
    return (unsigned short)(u >> 16);
}
__device__ __forceinline__ float bff(unsigned short s) {
    return __uint_as_float((unsigned int)s << 16);
}
__device__ __forceinline__ float fsig(float v)  { return 1.0f / (1.0f + __expf(-v)); }
__device__ __forceinline__ float ftanh(float v) { return 1.0f - 2.0f / (__expf(2.0f * v) + 1.0f); }

// ---- prep: build MFMA A-fragment streams (bf16 hi + Markidis lo), bias folded
// into column k==KREAL (acts supply a constant 1 there). frag slot f2 = hilo*1225+f,
// frag f = P[g] + kt*MT + mt; lane l holds A[mt*16 + (l&15)][kt*32 + (l>>4)*8 + j].
__global__ void __launch_bounds__(64)
prep_frags(const float* __restrict__ w_ih_e, const float* __restrict__ w_hh_e,
           const float* __restrict__ W1e,    const float* __restrict__ W2e,
           const float* __restrict__ Wmu,    const float* __restrict__ Wlv,
           const float* __restrict__ w_ih_d, const float* __restrict__ w_hh_d,
           const float* __restrict__ W1d,    const float* __restrict__ W2d,
           const float* __restrict__ Wo,
           const float* __restrict__ b_ih_e, const float* __restrict__ b_hh_e,
           const float* __restrict__ b1e,    const float* __restrict__ b2e,
           const float* __restrict__ bmu,    const float* __restrict__ blv,
           const float* __restrict__ b_ih_d, const float* __restrict__ b_hh_d,
           const float* __restrict__ b1d,    const float* __restrict__ b2d,
           const float* __restrict__ bo,
           unsigned short* __restrict__ ws)
{
    int f2 = blockIdx.x;
    int hilo = (f2 >= NFRAG) ? 1 : 0;
    int f = f2 - hilo * NFRAG;
    int g = 0;
    while (g < 11 && f >= P13[g + 1]) ++g;
    int fl = f - P13[g];
    int MT = MTa[g];
    int kt = fl / MT, mt = fl - kt * MT;

    const float* W; const float* bias;
    switch (g) {
        case 0:  W = w_ih_e; bias = b_ih_e; break;
        case 1:  W = w_hh_e; bias = b_hh_e; break;
        case 2:  W = W1e;    bias = b1e;    break;
        case 3:  W = W2e;    bias = b2e;    break;
        case 4:  W = Wmu;    bias = bmu;    break;
        case 5:  W = Wlv;    bias = blv;    break;
        case 6:  W = w_ih_d; bias = nullptr; break;   // x-part: bias goes with z-part
        case 7:  W = w_ih_d; bias = b_ih_d; break;
        case 8:  W = w_hh_d; bias = b_hh_d; break;
        case 9:  W = W1d;    bias = b1d;    break;
        case 10: W = W2d;    bias = b2d;    break;
        default: W = Wo;     bias = bo;     break;
    }
    int l = threadIdx.x;
    int m  = mt * 16 + (l & 15);
    int kb = kt * 32 + (l >> 4) * 8;
    unsigned short* dst = ws + (size_t)f2 * 512 + (size_t)l * 8;
    #pragma unroll
    for (int j = 0; j < 8; ++j) {
        int k = kb + j;
        float val = 0.0f;
        if (m < MREAL[g]) {
            if (k < KREAL[g]) val = W[(size_t)m * RSW[g] + COW[g] + k];
            else if (k == KREAL[g] && bias) val = bias[m];
        }
        unsigned short h = bfhi(val);
        if (hilo) h = bfhi(val - bff(h));
        dst[j] = h;
    }
}

// ---- per-wave GEMM: D[m][b] += W[m][k] * act[k][b], 3-term split.
// acts in LDS transposed [b][k] (bf16, row stride RS shorts).
// Weight fragments are read TEMPORAL (want L2 residency).
template<int MT, int KT, int NT, int RS>
__device__ __forceinline__ void wave_gemm(const short8v* __restrict__ Ahi,
                                          const short8v* __restrict__ Alo,
                                          const unsigned short* Bhi,
                                          const unsigned short* Blo,
                                          int w, int l, f32x4* acc)
{
    const int bo_ = (l & 15) * RS + (l >> 4) * 8;
    #pragma unroll
    for (int kt = 0; kt < KT; ++kt) {
        short8v bh = *(const short8v*)(Bhi + bo_ + kt * 32);
        short8v bl = *(const short8v*)(Blo + bo_ + kt * 32);
        #pragma unroll
        for (int i = 0; i < NT; ++i) {
            int mt = w + 8 * i;
            if (mt < MT) {
                short8v ah = Ahi[(size_t)(kt * MT + mt) * 64 + l];
                short8v al = Alo[(size_t)(kt * MT + mt) * 64 + l];
                acc[i] = __builtin_amdgcn_mfma_f32_16x16x32_bf16(ah, bl, acc[i], 0, 0, 0);
                acc[i] = __builtin_amdgcn_mfma_f32_16x16x32_bf16(al, bh, acc[i], 0, 0, 0);
                acc[i] = __builtin_amdgcn_mfma_f32_16x16x32_bf16(ah, bh, acc[i], 0, 0, 0);
            }
        }
    }
}

// tanh epilogue -> bf16 hi/lo transposed act buffer; skips padded m (protects bias-1 col)
__device__ __forceinline__ void write_tanh(const f32x4* acc, int NT_, int MT_, int Mreal_,
                                           unsigned short* Thi, unsigned short* Tlo,
                                           int RS_, int w, int l)
{
    int b = l & 15, q4 = (l >> 4) << 2;
    for (int i = 0; i < NT_; ++i) {
        int mt = w + 8 * i;
        if (mt < MT_) {
            #pragma unroll
            for (int r = 0; r < 4; ++r) {
                int m = mt * 16 + q4 + r;
                if (m < Mreal_) {
                    float v = ftanh(acc[i][r]);
                    unsigned short hi = bfhi(v);
                    Thi[b * RS_ + m] = hi;
                    Tlo[b * RS_ + m] = bfhi(v - bff(hi));
                }
            }
        }
    }
}

__global__ void __launch_bounds__(NTH, 2)
vae_mfma(const float* __restrict__ x, const short8v* __restrict__ wsv,
         float* __restrict__ out)
{
    // transposed act buffers [b][k] bf16 hi/lo
    __shared__ __align__(16) unsigned short xT_hi[NB * 168], xT_lo[NB * 168];
    __shared__ __align__(16) unsigned short hT_hi[NB * 168], hT_lo[NB * 168];
    __shared__ __align__(16) unsigned short m1T_hi[NB * 328], m1T_lo[NB * 328];
    __shared__ __align__(16) unsigned short m2T_hi[NB * 232], m2T_lo[NB * 232];
    __shared__ __align__(16) unsigned short zT_hi[NB * 168], zT_lo[NB * 168];

    const int tid = threadIdx.x;
    const int w = tid >> 6, l = tid & 63;
    const int bbase = blockIdx.x * NB;
    const size_t XREC_SZ = (size_t)T_STEPS * BT * NXV;
    const size_t MU_OFF = XREC_SZ;
    const size_t LV_OFF = XREC_SZ + (size_t)BT * NZV;
    const f32x4 z4 = {0.f, 0.f, 0.f, 0.f};

#define AHI(g) (wsv + (size_t)P13[g] * 64)
#define ALO(g) (wsv + (size_t)(NFRAG + P13[g]) * 64)

    // streaming tensors: non-temporal (evict-first) so weight frags stay L2-resident
    auto load_x = [&](int t, float xr[5]) {
        #pragma unroll
        for (int u = 0; u < 5; ++u) {
            int i = u * NTH + tid;
            if (i < NB * NXV)
                xr[u] = __builtin_nontemporal_load(
                    &x[(size_t)t * (BT * NXV) + (size_t)(bbase + i / NXV) * NXV + (i % NXV)]);
        }
    };
    auto store_x = [&](const float xr[5]) {
        #pragma unroll
        for (int u = 0; u < 5; ++u) {
            int i = u * NTH + tid;
            if (i < NB * NXV) {
                int b2 = i / NXV, k = i - b2 * NXV;
                unsigned short hi = bfhi(xr[u]);
                xT_hi[b2 * 168 + k] = hi;
                xT_lo[b2 * 168 + k] = bfhi(xr[u] - bff(hi));
            }
        }
    };

    float hreg[4] = {0.f, 0.f, 0.f, 0.f};
    auto gru_combine = [&](const f32x4* ai, const f32x4* ah) {
        #pragma unroll
        for (int r = 0; r < 4; ++r) {
            float rr = fsig(ai[0][r] + ah[0][r]);
            float zz = fsig(ai[1][r] + ah[1][r]);
            float nn = ftanh(ai[2][r] + rr * ah[2][r]);
            hreg[r] = (1.f - zz) * nn + zz * hreg[r];
        }
    };
    auto write_h = [&]() {
        int jb = w * 16 + ((l >> 4) << 2), b = l & 15;
        #pragma unroll
        for (int r = 0; r < 4; ++r) {
            unsigned short hi = bfhi(hreg[r]);
            hT_hi[b * 168 + jb + r] = hi;
            hT_lo[b * 168 + jb + r] = bfhi(hreg[r] - bff(hi));
        }
    };

    // ---- init: zero act buffers ----
    for (int i = tid; i < NB * 168; i += NTH) {
        xT_hi[i] = 0; xT_lo[i] = 0; hT_hi[i] = 0; hT_lo[i] = 0; zT_hi[i] = 0; zT_lo[i] = 0;
    }
    for (int i = tid; i < NB * 328; i += NTH) { m1T_hi[i] = 0; m1T_lo[i] = 0; }
    for (int i = tid; i < NB * 232; i += NTH) { m2T_hi[i] = 0; m2T_lo[i] = 0; }
    float xr[5] = {0, 0, 0, 0, 0};
    load_x(0, xr);
    __syncthreads();
    // bias-1 columns (persist: all rewrites skip these indices)
    if (tid < NB) {
        xT_hi[tid * 168 + 144] = 0x3F80;
        hT_hi[tid * 168 + 128] = 0x3F80;
        zT_hi[tid * 168 + 128] = 0x3F80;
        m1T_hi[tid * 328 + 300] = 0x3F80;
        m2T_hi[tid * 232 + 200] = 0x3F80;
    }
    store_x(xr);
    load_x(1, xr);
    __syncthreads();

    // ================= encoder GRU: 90 steps =================
    for (int t = 0; t < T_STEPS; ++t) {
        f32x4 ai[3] = {z4, z4, z4}, ah[3] = {z4, z4, z4};
        wave_gemm<24, 5, 3, 168>(AHI(0), ALO(0), xT_hi, xT_lo, w, l, ai);
        wave_gemm<24, 5, 3, 168>(AHI(1), ALO(1), hT_hi, hT_lo, w, l, ah);
        gru_combine(ai, ah);
        __syncthreads();             // all reads of hT/xT done
        write_h();
        if (t + 1 < T_STEPS) {
            store_x(xr);
            if (t + 2 < T_STEPS) load_x(t + 2, xr);
        }
        __syncthreads();
    }

    // ================= encoder MLP + latent heads =================
    {
        f32x4 a1[3] = {z4, z4, z4};
        wave_gemm<19, 5, 3, 168>(AHI(2), ALO(2), hT_hi, hT_lo, w, l, a1);
        write_tanh(a1, 3, 19, M1V, m1T_hi, m1T_lo, 328, w, l);
        __syncthreads();
        f32x4 a2[2] = {z4, z4};
        wave_gemm<13, 10, 2, 328>(AHI(3), ALO(3), m1T_hi, m1T_lo, w, l, a2);
        write_tanh(a2, 2, 13, M2V, m2T_hi, m2T_lo, 232, w, l);
        __syncthreads();
        f32x4 am[1] = {z4}, av[1] = {z4};
        wave_gemm<8, 7, 1, 232>(AHI(4), ALO(4), m2T_hi, m2T_lo, w, l, am);
        wave_gemm<8, 7, 1, 232>(AHI(5), ALO(5), m2T_hi, m2T_lo, w, l, av);
        int b = l & 15, q4 = (l >> 4) << 2;
        #pragma unroll
        for (int r = 0; r < 4; ++r) {
            int m = w * 16 + q4 + r;
            __builtin_nontemporal_store(am[0][r], &out[MU_OFF + (size_t)(bbase + b) * NZV + m]);
            __builtin_nontemporal_store(av[0][r], &out[LV_OFF + (size_t)(bbase + b) * NZV + m]);
            unsigned short hi = bfhi(am[0][r]);          // z = mu
            zT_hi[b * 168 + m] = hi;
            zT_lo[b * 168 + m] = bfhi(am[0][r] - bff(hi));
        }
    }
    __syncthreads();

    // ================= decoder init =================
    f32x4 gzr[3] = {z4, z4, z4};      // b_ih_d + W_ihd[:,144:272] @ z  (time-invariant)
    {
        for (int i = tid; i < NB * HV; i += NTH) {       // h0 = 0 (keep bias col)
            int b2 = i >> 7, j = i & 127;
            hT_hi[b2 * 168 + j] = 0; hT_lo[b2 * 168 + j] = 0;
        }
        float xr0[5] = {0, 0, 0, 0, 0};
        load_x(0, xr0);
        store_x(xr0);                                    // xp = x[0]
        wave_gemm<24, 5, 3, 168>(AHI(7), ALO(7), zT_hi, zT_lo, w, l, gzr);
        #pragma unroll
        for (int r = 0; r < 4; ++r) hreg[r] = 0.f;
    }
    __syncthreads();

    // ================= decoder: 90 autoregressive steps =================
    for (int t = 0; t < T_STEPS; ++t) {
        f32x4 ai[3], ah[3];
        #pragma unroll
        for (int i = 0; i < 3; ++i) { ai[i] = gzr[i]; ah[i] = z4; }
        wave_gemm<24, 5, 3, 168>(AHI(6), ALO(6), xT_hi, xT_lo, w, l, ai);
        wave_gemm<24, 5, 3, 168>(AHI(8), ALO(8), hT_hi, hT_lo, w, l, ah);
        gru_combine(ai, ah);
        __syncthreads();
        write_h();
        __syncthreads();
        f32x4 a1[3] = {z4, z4, z4};
        wave_gemm<19, 5, 3, 168>(AHI(9), ALO(9), hT_hi, hT_lo, w, l, a1);
        write_tanh(a1, 3, 19, M1V, m1T_hi, m1T_lo, 328, w, l);
        __syncthreads();
        f32x4 a2[2] = {z4, z4};
        wave_gemm<13, 10, 2, 328>(AHI(10), ALO(10), m1T_hi, m1T_lo, w, l, a2);
        write_tanh(a2, 2, 13, M2V, m2T_hi, m2T_lo, 232, w, l);
        __syncthreads();
        f32x4 ao[2] = {z4, z4};
        wave_gemm<9, 7, 2, 232>(AHI(11), ALO(11), m2T_hi, m2T_lo, w, l, ao);
        {   // epilogue: nt global store + autoregressive feedback
            int b = l & 15, q4 = (l >> 4) << 2;
            #pragma unroll
            for (int i2 = 0; i2 < 2; ++i2) {
                int mt = w + 8 * i2;
                if (mt < 9) {
                    #pragma unroll
                    for (int r = 0; r < 4; ++r) {
                        int m = mt * 16 + q4 + r;
                        float v = ao[i2][r];
                        __builtin_nontemporal_store(
                            v, &out[(size_t)t * (BT * NXV) + (size_t)(bbase + b) * NXV + m]);
                        unsigned short hi = bfhi(v);
                        xT_hi[b * 168 + m] = hi;
                        xT_lo[b * 168 + m] = bfhi(v - bff(hi));
                    }
                }
            }
        }
        __syncthreads();
    }
#undef AHI
#undef ALO
}

extern "C" void kernel_launch(void* const* d_in, const int* in_sizes, int n_in,
                              void* d_out, int out_size, void* d_ws, size_t ws_size,
                              hipStream_t stream) {
    (void)in_sizes; (void)n_in; (void)out_size; (void)ws_size;
    const float* p[23];
    for (int i = 0; i < 23; ++i) p[i] = (const float*)d_in[i];
    unsigned short* ws = (unsigned short*)d_ws;   // needs 2*1225 KB = 2.51 MB

    prep_frags<<<dim3(2 * NFRAG), dim3(64), 0, stream>>>(
        p[1], p[2], p[5], p[7], p[9], p[11], p[13], p[14], p[17], p[19], p[21],
        p[3], p[4], p[6], p[8], p[10], p[12], p[15], p[16], p[18], p[20], p[22],
        ws);

    vae_mfma<<<dim3(BT / NB), dim3(NTH), 0, stream>>>(
        p[0], (const short8v*)ws, (float*)d_out);
}

// Round 6
// 2569.082 us; speedup vs baseline: 1.9278x; 1.9278x over previous
//
#include <hip/hip_runtime.h>
#include <cstddef>

#define T_STEPS 90
#define BT      2048
#define NXV     144
#define HV      128
#define NZV     128
#define M1V     300
#define M2V     200
#define NB      32     // batches per workgroup (2 MFMA N-tiles)
#define NTH     1024   // 16 waves

typedef __attribute__((ext_vector_type(8))) _Float16 half8v;   // 8 fp16 (4 VGPRs)
typedef __attribute__((ext_vector_type(4))) float f32x4;

// ---- 12 fragment streams (fp16, single precision) ----
// g: 0 ENC_IH 1 ENC_HH 2 W1E 3 W2E 4 MU 5 LV 6 DEC_IHX 7 DEC_IHZ 8 DEC_HH 9 W1D 10 W2D 11 WO
constexpr int MTa[12]   = {24,24,19,13, 8, 8,24,24,24,19,13, 9};
constexpr int MREAL[12] = {384,384,300,200,128,128,384,384,384,300,200,144};
constexpr int KREAL[12] = {144,128,128,300,200,200,144,128,128,128,300,200};
constexpr int RSW[12]   = {144,128,128,300,200,200,272,272,128,128,300,200};
constexpr int COW[12]   = {  0,  0,  0,  0,  0,  0,  0,144,  0,  0,  0,  0};
constexpr int P13[13]   = {0,120,240,335,465,521,577,697,817,937,1032,1162,1225};
constexpr int NFRAG = 1225;   // 1225 frags x 1KB = 1.225 MB total (L2-resident)

__device__ __forceinline__ float fsig(float v)  { return 1.0f / (1.0f + __expf(-v)); }
__device__ __forceinline__ float ftanh(float v) { return 1.0f - 2.0f / (__expf(2.0f * v) + 1.0f); }

// ---- prep: fp16 MFMA A-fragment streams; bias folded into column k==KREAL
// (acts provide constant 1 there). frag f = P[g] + kt*MT + mt;
// lane l holds A[mt*16 + (l&15)][kt*32 + (l>>4)*8 + j].
__global__ void __launch_bounds__(64)
prep_frags(const float* __restrict__ w_ih_e, const float* __restrict__ w_hh_e,
           const float* __restrict__ W1e,    const float* __restrict__ W2e,
           const float* __restrict__ Wmu,    const float* __restrict__ Wlv,
           const float* __restrict__ w_ih_d, const float* __restrict__ w_hh_d,
           const float* __restrict__ W1d,    const float* __restrict__ W2d,
           const float* __restrict__ Wo,
           const float* __restrict__ b_ih_e, const float* __restrict__ b_hh_e,
           const float* __restrict__ b1e,    const float* __restrict__ b2e,
           const float* __restrict__ bmu,    const float* __restrict__ blv,
           const float* __restrict__ b_ih_d, const float* __restrict__ b_hh_d,
           const float* __restrict__ b1d,    const float* __restrict__ b2d,
           const float* __restrict__ bo,
           _Float16* __restrict__ ws)
{
    int f = blockIdx.x;
    int g = 0;
    while (g < 11 && f >= P13[g + 1]) ++g;
    int fl = f - P13[g];
    int MT = MTa[g];
    int kt = fl / MT, mt = fl - kt * MT;

    const float* W; const float* bias;
    switch (g) {
        case 0:  W = w_ih_e; bias = b_ih_e; break;
        case 1:  W = w_hh_e; bias = b_hh_e; break;
        case 2:  W = W1e;    bias = b1e;    break;
        case 3:  W = W2e;    bias = b2e;    break;
        case 4:  W = Wmu;    bias = bmu;    break;
        case 5:  W = Wlv;    bias = blv;    break;
        case 6:  W = w_ih_d; bias = nullptr; break;   // x-part: bias rides with z-part
        case 7:  W = w_ih_d; bias = b_ih_d; break;
        case 8:  W = w_hh_d; bias = b_hh_d; break;
        case 9:  W = W1d;    bias = b1d;    break;
        case 10: W = W2d;    bias = b2d;    break;
        default: W = Wo;     bias = bo;     break;
    }
    int l = threadIdx.x;
    int m  = mt * 16 + (l & 15);
    int kb = kt * 32 + (l >> 4) * 8;
    _Float16* dst = ws + (size_t)f * 512 + (size_t)l * 8;
    #pragma unroll
    for (int j = 0; j < 8; ++j) {
        int k = kb + j;
        float val = 0.0f;
        if (m < MREAL[g]) {
            if (k < KREAL[g]) val = W[(size_t)m * RSW[g] + COW[g] + k];
            else if (k == KREAL[g] && bias) val = bias[m];
        }
        dst[j] = (_Float16)val;   // RNE
    }
}

// ---- gate GEMM (MT=24 groups): wave halves split the 2 batch N-tiles so that
// r/z/n of the same hidden unit land in the same lane (register GRU combine).
// wave w: half = w>>3 (batch tile), wsub = w&7 owns M-tiles {wsub, wsub+8, wsub+16}.
template<int KT, int RS>
__device__ __forceinline__ void gate_gemm(const half8v* __restrict__ A,
                                          const _Float16* __restrict__ Bt,
                                          int w, int l, f32x4 acc[3])
{
    const int half_ = w >> 3, wsub = w & 7;
    const int bo_ = ((l & 15) + 16 * half_) * RS + ((l >> 4) << 3);
    #pragma unroll
    for (int kt = 0; kt < KT; ++kt) {
        half8v bf = *(const half8v*)(Bt + bo_ + kt * 32);
        #pragma unroll
        for (int j = 0; j < 3; ++j) {
            half8v af = A[(size_t)(kt * 24 + wsub + 8 * j) * 64 + l];
            acc[j] = __builtin_amdgcn_mfma_f32_16x16x32_f16(af, bf, acc[j], 0, 0, 0);
        }
    }
}

// ---- MLP GEMM: wave w owns M-tiles w + 16*i, computes both batch N-tiles.
template<int MT, int KT, int NT2, int RS>
__device__ __forceinline__ void mlp_gemm(const half8v* __restrict__ A,
                                         const _Float16* __restrict__ Bt,
                                         int w, int l, f32x4 acc[NT2][2])
{
    const int bo_ = (l & 15) * RS + ((l >> 4) << 3);
    #pragma unroll
    for (int kt = 0; kt < KT; ++kt) {
        half8v b0 = *(const half8v*)(Bt + bo_ + kt * 32);
        half8v b1 = *(const half8v*)(Bt + bo_ + 16 * RS + kt * 32);
        #pragma unroll
        for (int i = 0; i < NT2; ++i) {
            int mt = w + 16 * i;
            if (mt < MT) {
                half8v af = A[(size_t)(kt * MT + mt) * 64 + l];
                acc[i][0] = __builtin_amdgcn_mfma_f32_16x16x32_f16(af, b0, acc[i][0], 0, 0, 0);
                acc[i][1] = __builtin_amdgcn_mfma_f32_16x16x32_f16(af, b1, acc[i][1], 0, 0, 0);
            }
        }
    }
}

// ---- latent-head GEMM (MT=8): wsub in 0..7 owns M-tile wsub, both N-tiles.
template<int KT, int RS>
__device__ __forceinline__ void head_gemm(const half8v* __restrict__ A,
                                          const _Float16* __restrict__ Bt,
                                          int wsub, int l, f32x4 acc[2])
{
    const int bo_ = (l & 15) * RS + ((l >> 4) << 3);
    #pragma unroll
    for (int kt = 0; kt < KT; ++kt) {
        half8v b0 = *(const half8v*)(Bt + bo_ + kt * 32);
        half8v b1 = *(const half8v*)(Bt + bo_ + 16 * RS + kt * 32);
        half8v af = A[(size_t)(kt * 8 + wsub) * 64 + l];
        acc[0] = __builtin_amdgcn_mfma_f32_16x16x32_f16(af, b0, acc[0], 0, 0, 0);
        acc[1] = __builtin_amdgcn_mfma_f32_16x16x32_f16(af, b1, acc[1], 0, 0, 0);
    }
}

// tanh epilogue -> fp16 act buffer, both N-tiles; masks padded m (protects bias col)
template<int MT, int NT2, int RS>
__device__ __forceinline__ void write_tanh2(const f32x4 acc[NT2][2], int Mreal,
                                            _Float16* __restrict__ T, int w, int l)
{
    int b = l & 15, q4 = (l >> 4) << 2;
    #pragma unroll
    for (int i = 0; i < NT2; ++i) {
        int mt = w + 16 * i;
        if (mt < MT) {
            #pragma unroll
            for (int r = 0; r < 4; ++r) {
                int m = mt * 16 + q4 + r;
                if (m < Mreal) {
                    T[b * RS + m]        = (_Float16)ftanh(acc[i][0][r]);
                    T[(b + 16) * RS + m] = (_Float16)ftanh(acc[i][1][r]);
                }
            }
        }
    }
}

__global__ void __launch_bounds__(NTH)
vae_mfma(const float* __restrict__ x, const half8v* __restrict__ wsv,
         float* __restrict__ out)
{
    // fp16 act buffers, transposed [b][k]; k-pad beyond KREAL must stay zero,
    // bias col (k==KREAL) holds constant 1.
    __shared__ __align__(16) _Float16 xT [NB * 168];
    __shared__ __align__(16) _Float16 hT [NB * 168];
    __shared__ __align__(16) _Float16 m1T[NB * 328];
    __shared__ __align__(16) _Float16 m2T[NB * 232];
    __shared__ __align__(16) _Float16 zT [NB * 168];

    const int tid = threadIdx.x;
    const int w = tid >> 6, l = tid & 63;
    const int bbase = blockIdx.x * NB;
    const size_t XREC_SZ = (size_t)T_STEPS * BT * NXV;
    const size_t MU_OFF = XREC_SZ;
    const size_t LV_OFF = XREC_SZ + (size_t)BT * NZV;
    const f32x4 z4 = {0.f, 0.f, 0.f, 0.f};

#define AHI(g) (wsv + (size_t)P13[g] * 64)

    auto load_x = [&](int t, float xr[5]) {
        #pragma unroll
        for (int u = 0; u < 5; ++u) {
            int i = u * NTH + tid;
            if (i < NB * NXV)
                xr[u] = __builtin_nontemporal_load(
                    &x[(size_t)t * (BT * NXV) + (size_t)(bbase + i / NXV) * NXV + (i % NXV)]);
        }
    };
    auto store_x = [&](const float xr[5]) {
        #pragma unroll
        for (int u = 0; u < 5; ++u) {
            int i = u * NTH + tid;
            if (i < NB * NXV) {
                int b2 = i / NXV, k = i - b2 * NXV;
                xT[b2 * 168 + k] = (_Float16)xr[u];
            }
        }
    };

    // per-wave hidden state: unit j = 16*(w&7) + (l>>4)*4 + r, batch (l&15)+16*(w>>3)
    float hreg[4] = {0.f, 0.f, 0.f, 0.f};
    auto gru_combine = [&](const f32x4* ai, const f32x4* ah) {
        #pragma unroll
        for (int r = 0; r < 4; ++r) {
            float rr = fsig(ai[0][r] + ah[0][r]);
            float zz = fsig(ai[1][r] + ah[1][r]);
            float nn = ftanh(ai[2][r] + rr * ah[2][r]);
            hreg[r] = (1.f - zz) * nn + zz * hreg[r];
        }
    };
    auto write_h = [&]() {
        int jb = 16 * (w & 7) + ((l >> 4) << 2);
        int b  = (l & 15) + 16 * (w >> 3);
        #pragma unroll
        for (int r = 0; r < 4; ++r) hT[b * 168 + jb + r] = (_Float16)hreg[r];
    };

    // ---- init: zero all act buffers (k-pad correctness) ----
    for (int i = tid; i < NB * 168; i += NTH) { xT[i] = (_Float16)0.f; hT[i] = (_Float16)0.f; zT[i] = (_Float16)0.f; }
    for (int i = tid; i < NB * 328; i += NTH) m1T[i] = (_Float16)0.f;
    for (int i = tid; i < NB * 232; i += NTH) m2T[i] = (_Float16)0.f;
    float xr[5] = {0, 0, 0, 0, 0};
    load_x(0, xr);
    __syncthreads();
    if (tid < NB) {   // bias-1 columns (persist; all rewrites skip these)
        xT [tid * 168 + 144] = (_Float16)1.f;
        hT [tid * 168 + 128] = (_Float16)1.f;
        zT [tid * 168 + 128] = (_Float16)1.f;
        m1T[tid * 328 + 300] = (_Float16)1.f;
        m2T[tid * 232 + 200] = (_Float16)1.f;
    }
    store_x(xr);
    load_x(1, xr);
    __syncthreads();

    // ================= encoder GRU: 90 steps =================
    for (int t = 0; t < T_STEPS; ++t) {
        f32x4 ai[3] = {z4, z4, z4}, ah[3] = {z4, z4, z4};
        gate_gemm<5, 168>(AHI(0), xT, w, l, ai);
        gate_gemm<5, 168>(AHI(1), hT, w, l, ah);
        gru_combine(ai, ah);
        __syncthreads();              // all reads of xT/hT done
        write_h();
        if (t + 1 < T_STEPS) {
            store_x(xr);
            if (t + 2 < T_STEPS) load_x(t + 2, xr);
        }
        __syncthreads();
    }

    // ================= encoder MLP + latent heads =================
    {
        f32x4 a1[2][2] = {{z4, z4}, {z4, z4}};
        mlp_gemm<19, 5, 2, 168>(AHI(2), hT, w, l, a1);
        write_tanh2<19, 2, 328>(a1, M1V, m1T, w, l);
        __syncthreads();
        f32x4 a2[1][2] = {{z4, z4}};
        mlp_gemm<13, 10, 1, 328>(AHI(3), m1T, w, l, a2);
        write_tanh2<13, 1, 232>(a2, M2V, m2T, w, l);
        __syncthreads();
        f32x4 ah2[2] = {z4, z4};
        if (w < 8) head_gemm<7, 232>(AHI(4), m2T, w, l, ah2);        // mu
        else       head_gemm<7, 232>(AHI(5), m2T, w - 8, l, ah2);    // logvar
        int b = l & 15, q4 = (l >> 4) << 2;
        int m = (w & 7) * 16 + q4;
        if (w < 8) {
            __builtin_nontemporal_store(ah2[0], (f32x4*)&out[MU_OFF + (size_t)(bbase + b) * NZV + m]);
            __builtin_nontemporal_store(ah2[1], (f32x4*)&out[MU_OFF + (size_t)(bbase + b + 16) * NZV + m]);
            #pragma unroll
            for (int r = 0; r < 4; ++r) {            // z = mu
                zT[b * 168 + m + r]        = (_Float16)ah2[0][r];
                zT[(b + 16) * 168 + m + r] = (_Float16)ah2[1][r];
            }
        } else {
            __builtin_nontemporal_store(ah2[0], (f32x4*)&out[LV_OFF + (size_t)(bbase + b) * NZV + m]);
            __builtin_nontemporal_store(ah2[1], (f32x4*)&out[LV_OFF + (size_t)(bbase + b + 16) * NZV + m]);
        }
    }
    __syncthreads();

    // ================= decoder init =================
    f32x4 gzr[3] = {z4, z4, z4};   // b_ih_d + W_ihd[:,144:272] @ z  (time-invariant)
    {
        for (int i = tid; i < NB * HV; i += NTH) {     // h0 = 0 (keep bias col)
            int b2 = i >> 7, j = i & 127;
            hT[b2 * 168 + j] = (_Float16)0.f;
        }
        float xr0[5] = {0, 0, 0, 0, 0};
        load_x(0, xr0);
        store_x(xr0);                                  // xp = x[0]
        gate_gemm<5, 168>(AHI(7), zT, w, l, gzr);
        #pragma unroll
        for (int r = 0; r < 4; ++r) hreg[r] = 0.f;
    }
    __syncthreads();

    // ================= decoder: 90 autoregressive steps =================
    for (int t = 0; t < T_STEPS; ++t) {
        f32x4 ai[3], ah[3];
        #pragma unroll
        for (int i = 0; i < 3; ++i) { ai[i] = gzr[i]; ah[i] = z4; }
        gate_gemm<5, 168>(AHI(6), xT, w, l, ai);
        gate_gemm<5, 168>(AHI(8), hT, w, l, ah);
        gru_combine(ai, ah);
        __syncthreads();
        write_h();
        __syncthreads();
        f32x4 a1[2][2] = {{z4, z4}, {z4, z4}};
        mlp_gemm<19, 5, 2, 168>(AHI(9), hT, w, l, a1);
        write_tanh2<19, 2, 328>(a1, M1V, m1T, w, l);
        __syncthreads();
        f32x4 a2[1][2] = {{z4, z4}};
        mlp_gemm<13, 10, 1, 328>(AHI(10), m1T, w, l, a2);
        write_tanh2<13, 1, 232>(a2, M2V, m2T, w, l);
        __syncthreads();
        f32x4 ao[1][2] = {{z4, z4}};
        mlp_gemm<9, 7, 1, 232>(AHI(11), m2T, w, l, ao);
        if (w < 9) {   // epilogue: nt global store (16B) + fp16 feedback
            int b = l & 15, q4 = (l >> 4) << 2;
            int m = w * 16 + q4;
            __builtin_nontemporal_store(ao[0][0],
                (f32x4*)&out[(size_t)t * (BT * NXV) + (size_t)(bbase + b) * NXV + m]);
            __builtin_nontemporal_store(ao[0][1],
                (f32x4*)&out[(size_t)t * (BT * NXV) + (size_t)(bbase + b + 16) * NXV + m]);
            #pragma unroll
            for (int r = 0; r < 4; ++r) {
                xT[b * 168 + m + r]        = (_Float16)ao[0][0][r];
                xT[(b + 16) * 168 + m + r] = (_Float16)ao[0][1][r];
            }
        }
        __syncthreads();
    }
#undef AHI
}

extern "C" void kernel_launch(void* const* d_in, const int* in_sizes, int n_in,
                              void* d_out, int out_size, void* d_ws, size_t ws_size,
                              hipStream_t stream) {
    (void)in_sizes; (void)n_in; (void)out_size; (void)ws_size;
    const float* p[23];
    for (int i = 0; i < 23; ++i) p[i] = (const float*)d_in[i];
    _Float16* ws = (_Float16*)d_ws;   // 1225 KB

    prep_frags<<<dim3(NFRAG), dim3(64), 0, stream>>>(
        p[1], p[2], p[5], p[7], p[9], p[11], p[13], p[14], p[17], p[19], p[21],
        p[3], p[4], p[6], p[8], p[10], p[12], p[15], p[16], p[18], p[20], p[22],
        ws);

    vae_mfma<<<dim3(BT / NB), dim3(NTH), 0, stream>>>(
        p[0], (const half8v*)ws, (float*)d_out);
}

// Round 7
// 882.512 us; speedup vs baseline: 5.6121x; 2.9111x over previous
//
#include <hip/hip_runtime.h>
#include <cstddef>

#define T_STEPS 90
#define BT      2048
#define NXV     144
#define HV      128
#define NZV     128
#define M1V     300
#define M2V     200
#define NB      16     // batches per workgroup (1 MFMA N-tile)
#define NTH     512    // 8 waves

typedef __attribute__((ext_vector_type(8))) _Float16 half8v;   // 8 fp16 (4 VGPRs)
typedef __attribute__((ext_vector_type(4))) float f32x4;

// ---- 12 fragment streams (fp16) ----
// g: 0 ENC_IH 1 ENC_HH 2 W1E 3 W2E 4 MU 5 LV 6 DEC_IHX 7 DEC_IHZ 8 DEC_HH 9 W1D 10 W2D 11 WO
constexpr int MTa[12]   = {24,24,19,13, 8, 8,24,24,24,19,13, 9};
constexpr int MREAL[12] = {384,384,300,200,128,128,384,384,384,300,200,144};
constexpr int KREAL[12] = {144,128,128,300,200,200,144,128,128,128,300,200};
constexpr int RSW[12]   = {144,128,128,300,200,200,272,272,128,128,300,200};
constexpr int COW[12]   = {  0,  0,  0,  0,  0,  0,  0,144,  0,  0,  0,  0};
constexpr int P13[13]   = {0,120,240,335,465,521,577,697,817,937,1032,1162,1225};
constexpr int NFRAG = 1225;   // 1225 frags x 1KB = 1.225 MB (L2-resident)

__device__ __forceinline__ float fsig(float v)  { return 1.0f / (1.0f + __expf(-v)); }
__device__ __forceinline__ float ftanh(float v) { return 1.0f - 2.0f / (__expf(2.0f * v) + 1.0f); }

// ---- prep: fp16 MFMA A-fragment streams; bias folded into column k==KREAL ----
__global__ void __launch_bounds__(64)
prep_frags(const float* __restrict__ w_ih_e, const float* __restrict__ w_hh_e,
           const float* __restrict__ W1e,    const float* __restrict__ W2e,
           const float* __restrict__ Wmu,    const float* __restrict__ Wlv,
           const float* __restrict__ w_ih_d, const float* __restrict__ w_hh_d,
           const float* __restrict__ W1d,    const float* __restrict__ W2d,
           const float* __restrict__ Wo,
           const float* __restrict__ b_ih_e, const float* __restrict__ b_hh_e,
           const float* __restrict__ b1e,    const float* __restrict__ b2e,
           const float* __restrict__ bmu,    const float* __restrict__ blv,
           const float* __restrict__ b_ih_d, const float* __restrict__ b_hh_d,
           const float* __restrict__ b1d,    const float* __restrict__ b2d,
           const float* __restrict__ bo,
           _Float16* __restrict__ ws)
{
    int f = blockIdx.x;
    int g = 0;
    while (g < 11 && f >= P13[g + 1]) ++g;
    int fl = f - P13[g];
    int MT = MTa[g];
    int kt = fl / MT, mt = fl - kt * MT;

    const float* W; const float* bias;
    switch (g) {
        case 0:  W = w_ih_e; bias = b_ih_e; break;
        case 1:  W = w_hh_e; bias = b_hh_e; break;
        case 2:  W = W1e;    bias = b1e;    break;
        case 3:  W = W2e;    bias = b2e;    break;
        case 4:  W = Wmu;    bias = bmu;    break;
        case 5:  W = Wlv;    bias = blv;    break;
        case 6:  W = w_ih_d; bias = nullptr; break;
        case 7:  W = w_ih_d; bias = b_ih_d; break;
        case 8:  W = w_hh_d; bias = b_hh_d; break;
        case 9:  W = W1d;    bias = b1d;    break;
        case 10: W = W2d;    bias = b2d;    break;
        default: W = Wo;     bias = bo;     break;
    }
    int l = threadIdx.x;
    int m  = mt * 16 + (l & 15);
    int kb = kt * 32 + (l >> 4) * 8;
    _Float16* dst = ws + (size_t)f * 512 + (size_t)l * 8;
    #pragma unroll
    for (int j = 0; j < 8; ++j) {
        int k = kb + j;
        float val = 0.0f;
        if (m < MREAL[g]) {
            if (k < KREAL[g]) val = W[(size_t)m * RSW[g] + COW[g] + k];
            else if (k == KREAL[g] && bias) val = bias[m];
        }
        dst[j] = (_Float16)val;
    }
}

// ---- gate GEMM from REGISTER-resident fragments (15 frags = tiles {w,w+8,w+16} x 5 kt)
template<int RS>
__device__ __forceinline__ void gate_gemm_reg(const half8v (&gw)[15],
                                              const _Float16* __restrict__ Bt,
                                              int l, f32x4 (&acc)[3])
{
    const int bo_ = (l & 15) * RS + ((l >> 4) << 3);
    #pragma unroll
    for (int kt = 0; kt < 5; ++kt) {
        half8v bf = *(const half8v*)(Bt + bo_ + kt * 32);
        #pragma unroll
        for (int j = 0; j < 3; ++j)
            acc[j] = __builtin_amdgcn_mfma_f32_16x16x32_f16(gw[kt * 3 + j], bf, acc[j], 0, 0, 0);
    }
}

// ---- streamed GEMM: prefetch ALL A-frags to registers, then MFMA. Wave w owns
// M-tiles w+8*i. (gate-style {w,w+8,w+16} is the NT=3, MT=24 instance.)
template<int MT, int KT, int NT, int RS>
__device__ __forceinline__ void mlp_stream(const half8v* __restrict__ A,
                                           const _Float16* __restrict__ Bt,
                                           int w, int l, f32x4 (&acc)[NT])
{
    half8v af[NT * KT];
    #pragma unroll
    for (int i = 0; i < NT; ++i) {
        int mt = w + 8 * i;
        if (mt < MT) {
            #pragma unroll
            for (int kt = 0; kt < KT; ++kt)
                af[i * KT + kt] = A[(size_t)(kt * MT + mt) * 64 + l];
        }
    }
    const int bo_ = (l & 15) * RS + ((l >> 4) << 3);
    #pragma unroll
    for (int kt = 0; kt < KT; ++kt) {
        half8v bf = *(const half8v*)(Bt + bo_ + kt * 32);
        #pragma unroll
        for (int i = 0; i < NT; ++i) {
            int mt = w + 8 * i;
            if (mt < MT)
                acc[i] = __builtin_amdgcn_mfma_f32_16x16x32_f16(af[i * KT + kt], bf, acc[i], 0, 0, 0);
        }
    }
}

// ---- GEMM with A staged in LDS (conflict-free: lane stride 16B) ----
template<int MT, int KT, int NT, int RS>
__device__ __forceinline__ void mlp_lds(const _Float16* __restrict__ Alds,
                                        const _Float16* __restrict__ Bt,
                                        int w, int l, f32x4 (&acc)[NT])
{
    const int bo_ = (l & 15) * RS + ((l >> 4) << 3);
    #pragma unroll
    for (int kt = 0; kt < KT; ++kt) {
        half8v bf = *(const half8v*)(Bt + bo_ + kt * 32);
        #pragma unroll
        for (int i = 0; i < NT; ++i) {
            int mt = w + 8 * i;
            if (mt < MT) {
                half8v af = *(const half8v*)(Alds + ((size_t)(kt * MT + mt) * 64 + l) * 8);
                acc[i] = __builtin_amdgcn_mfma_f32_16x16x32_f16(af, bf, acc[i], 0, 0, 0);
            }
        }
    }
}

// tanh epilogue -> fp16 act buffer (single N-tile); masks padded m (protects bias col)
template<int MT, int NT, int RS>
__device__ __forceinline__ void write_tanhN(const f32x4 (&acc)[NT], int Mreal,
                                            _Float16* __restrict__ T, int w, int l)
{
    int b = l & 15, q4 = (l >> 4) << 2;
    #pragma unroll
    for (int i = 0; i < NT; ++i) {
        int mt = w + 8 * i;
        if (mt < MT) {
            #pragma unroll
            for (int r = 0; r < 4; ++r) {
                int m = mt * 16 + q4 + r;
                if (m < Mreal) T[b * RS + m] = (_Float16)ftanh(acc[i][r]);
            }
        }
    }
}

__global__ void __launch_bounds__(NTH, 2)
vae_mfma(const float* __restrict__ x, const half8v* __restrict__ wsv,
         float* __restrict__ out)
{
    // act buffers [b][k] fp16 (k-pad zero, bias col = 1); W2d staged in LDS.
    __shared__ __align__(16) _Float16 xT [NB * 168];
    __shared__ __align__(16) _Float16 hT [NB * 168];
    __shared__ __align__(16) _Float16 m1T[NB * 328];   // doubles as zT (RS=328)
    __shared__ __align__(16) _Float16 m2T[NB * 232];
    __shared__ __align__(16) _Float16 g10L[130 * 512]; // W2d frags (130 KB)

    const int tid = threadIdx.x;
    const int w = tid >> 6, l = tid & 63;
    const int bbase = blockIdx.x * NB;
    const size_t XREC_SZ = (size_t)T_STEPS * BT * NXV;
    const size_t MU_OFF = XREC_SZ;
    const size_t LV_OFF = XREC_SZ + (size_t)BT * NZV;
    const f32x4 z4 = {0.f, 0.f, 0.f, 0.f};

#define AHI(g) (wsv + (size_t)P13[g] * 64)

    auto load_x = [&](int t, float xr[5]) {
        #pragma unroll
        for (int u = 0; u < 5; ++u) {
            int i = u * NTH + tid;
            if (i < NB * NXV)
                xr[u] = __builtin_nontemporal_load(
                    &x[(size_t)t * (BT * NXV) + (size_t)(bbase + i / NXV) * NXV + (i % NXV)]);
        }
    };
    auto store_x = [&](const float xr[5]) {
        #pragma unroll
        for (int u = 0; u < 5; ++u) {
            int i = u * NTH + tid;
            if (i < NB * NXV) {
                int b2 = i / NXV, k = i - b2 * NXV;
                xT[b2 * 168 + k] = (_Float16)xr[u];
            }
        }
    };

    // register-resident gate fragments (reloaded for decoder)
    half8v gih[15], ghh[15];
    auto load_gates = [&](const half8v* Gih, const half8v* Ghh) {
        #pragma unroll
        for (int kt = 0; kt < 5; ++kt) {
            #pragma unroll
            for (int j = 0; j < 3; ++j) {
                gih[kt * 3 + j] = Gih[(size_t)(kt * 24 + w + 8 * j) * 64 + l];
                ghh[kt * 3 + j] = Ghh[(size_t)(kt * 24 + w + 8 * j) * 64 + l];
            }
        }
    };

    // per-wave hidden state: unit j = 16*w + (l>>4)*4 + r, batch l&15
    float hreg[4] = {0.f, 0.f, 0.f, 0.f};
    auto gru_combine = [&](const f32x4 (&ai)[3], const f32x4 (&ah)[3]) {
        #pragma unroll
        for (int r = 0; r < 4; ++r) {
            float rr = fsig(ai[0][r] + ah[0][r]);
            float zz = fsig(ai[1][r] + ah[1][r]);
            float nn = ftanh(ai[2][r] + rr * ah[2][r]);
            hreg[r] = (1.f - zz) * nn + zz * hreg[r];
        }
    };
    auto write_h = [&]() {
        int jb = 16 * w + ((l >> 4) << 2), b = l & 15;
        #pragma unroll
        for (int r = 0; r < 4; ++r) hT[b * 168 + jb + r] = (_Float16)hreg[r];
    };

    // ---- init: zero act buffers; stage W2d into LDS; load encoder gate frags ----
    for (int i = tid; i < NB * 168; i += NTH) { xT[i] = (_Float16)0.f; hT[i] = (_Float16)0.f; }
    for (int i = tid; i < NB * 328; i += NTH) m1T[i] = (_Float16)0.f;
    for (int i = tid; i < NB * 232; i += NTH) m2T[i] = (_Float16)0.f;
    for (int i = tid; i < 130 * 64; i += NTH)
        *(half8v*)(g10L + (size_t)i * 8) = AHI(10)[i];
    load_gates(AHI(0), AHI(1));
    float xr[5] = {0, 0, 0, 0, 0};
    load_x(0, xr);
    __syncthreads();
    if (tid < NB) {   // bias-1 columns (persist; rewrites skip these)
        xT [tid * 168 + 144] = (_Float16)1.f;
        hT [tid * 168 + 128] = (_Float16)1.f;
        m1T[tid * 328 + 300] = (_Float16)1.f;
        m2T[tid * 232 + 200] = (_Float16)1.f;
    }
    store_x(xr);
    load_x(1, xr);
    __syncthreads();

    // ================= encoder GRU: 90 steps (zero global loads in gates) =====
    for (int t = 0; t < T_STEPS; ++t) {
        f32x4 ai[3] = {z4, z4, z4}, ah[3] = {z4, z4, z4};
        gate_gemm_reg<168>(gih, xT, l, ai);
        gate_gemm_reg<168>(ghh, hT, l, ah);
        gru_combine(ai, ah);
        __syncthreads();              // all reads of xT/hT done
        write_h();
        if (t + 1 < T_STEPS) {
            store_x(xr);
            if (t + 2 < T_STEPS) load_x(t + 2, xr);
        }
        __syncthreads();
    }

    // ================= encoder MLP + latent heads =================
    {
        f32x4 a1[3] = {z4, z4, z4};
        mlp_stream<19, 5, 3, 168>(AHI(2), hT, w, l, a1);
        write_tanhN<19, 3, 328>(a1, M1V, m1T, w, l);
        __syncthreads();
        f32x4 a2[2] = {z4, z4};
        mlp_stream<13, 10, 2, 328>(AHI(3), m1T, w, l, a2);
        write_tanhN<13, 2, 232>(a2, M2V, m2T, w, l);
        __syncthreads();
        f32x4 am[1] = {z4}, av[1] = {z4};
        mlp_stream<8, 7, 1, 232>(AHI(4), m2T, w, l, am);   // mu (tile w)
        mlp_stream<8, 7, 1, 232>(AHI(5), m2T, w, l, av);   // logvar
        __syncthreads();   // m1T reads (g3) done -> safe to overwrite with z
        int b = l & 15, q4 = (l >> 4) << 2;
        int m = w * 16 + q4;
        __builtin_nontemporal_store(am[0], (f32x4*)&out[MU_OFF + (size_t)(bbase + b) * NZV + m]);
        __builtin_nontemporal_store(av[0], (f32x4*)&out[LV_OFF + (size_t)(bbase + b) * NZV + m]);
        #pragma unroll
        for (int r = 0; r < 4; ++r)            // z = mu -> m1T-as-zT (RS=328)
            m1T[b * 328 + m + r] = (_Float16)am[0][r];
    }

    // ================= decoder init =================
    f32x4 gzr[3] = {z4, z4, z4};   // b_ih_d + W_ihd[:,144:272] @ z (time-invariant)
    {
        for (int i = tid; i < NB * HV; i += NTH) {     // h0 = 0 (keep bias col)
            int b2 = i >> 7, j = i & 127;
            hT[b2 * 168 + j] = (_Float16)0.f;
        }
        if (tid < NB) m1T[tid * 328 + 128] = (_Float16)1.f;   // z bias col
        float xr0[5] = {0, 0, 0, 0, 0};
        load_x(0, xr0);
        store_x(xr0);                                  // xp = x[0]
        __syncthreads();                               // z + bias visible
        mlp_stream<24, 5, 3, 328>(AHI(7), m1T, w, l, gzr);
        load_gates(AHI(6), AHI(8));                    // decoder gate frags -> regs
        #pragma unroll
        for (int r = 0; r < 4; ++r) hreg[r] = 0.f;
    }
    __syncthreads();

    // ================= decoder: 90 autoregressive steps =================
    for (int t = 0; t < T_STEPS; ++t) {
        f32x4 ai[3], ah[3];
        #pragma unroll
        for (int i = 0; i < 3; ++i) { ai[i] = gzr[i]; ah[i] = z4; }
        gate_gemm_reg<168>(gih, xT, l, ai);
        gate_gemm_reg<168>(ghh, hT, l, ah);
        gru_combine(ai, ah);
        __syncthreads();          // gzr reads of m1T (t==0) + gate reads done
        write_h();
        __syncthreads();
        f32x4 a1[3] = {z4, z4, z4};
        mlp_stream<19, 5, 3, 168>(AHI(9), hT, w, l, a1);   // W1d: L2 stream
        write_tanhN<19, 3, 328>(a1, M1V, m1T, w, l);
        __syncthreads();
        f32x4 a2[2] = {z4, z4};
        mlp_lds<13, 10, 2, 328>(g10L, m1T, w, l, a2);      // W2d: LDS-resident
        write_tanhN<13, 2, 232>(a2, M2V, m2T, w, l);
        __syncthreads();
        f32x4 ao[2] = {z4, z4};
        mlp_stream<9, 7, 2, 232>(AHI(11), m2T, w, l, ao);  // Wo: L2 stream
        {   // epilogue: nt global store (16B) + fp16 feedback into xT
            int b = l & 15, q4 = (l >> 4) << 2;
            #pragma unroll
            for (int i2 = 0; i2 < 2; ++i2) {
                int mt = w + 8 * i2;
                if (mt < 9) {
                    int m = mt * 16 + q4;
                    __builtin_nontemporal_store(ao[i2],
                        (f32x4*)&out[(size_t)t * (BT * NXV) + (size_t)(bbase + b) * NXV + m]);
                    #pragma unroll
                    for (int r = 0; r < 4; ++r)
                        xT[b * 168 + m + r] = (_Float16)ao[i2][r];
                }
            }
        }
        __syncthreads();
    }
#undef AHI
}

extern "C" void kernel_launch(void* const* d_in, const int* in_sizes, int n_in,
                              void* d_out, int out_size, void* d_ws, size_t ws_size,
                              hipStream_t stream) {
    (void)in_sizes; (void)n_in; (void)out_size; (void)ws_size;
    const float* p[23];
    for (int i = 0; i < 23; ++i) p[i] = (const float*)d_in[i];
    _Float16* ws = (_Float16*)d_ws;   // 1225 KB

    prep_frags<<<dim3(NFRAG), dim3(64), 0, stream>>>(
        p[1], p[2], p[5], p[7], p[9], p[11], p[13], p[14], p[17], p[19], p[21],
        p[3], p[4], p[6], p[8], p[10], p[12], p[15], p[16], p[18], p[20], p[22],
        ws);

    vae_mfma<<<dim3(BT / NB), dim3(NTH), 0, stream>>>(
        p[0], (const half8v*)ws, (float*)d_out);
}